// Round 2
// baseline (1369.757 us; speedup 1.0000x reference)
//
#include <hip/hip_runtime.h>

// Experts FFN: out[b,e,n,d] = gelu(x[b,e] @ w1[e] + b1[e]) @ w2[e] + b2[e]
// B=4 E=8 N=1024 D=1024 H=4096, fp32 in/out, bf16 MFMA internally.
//
// Round 2 (resubmit; round-1 bench was an infra failure, no kernel signal):
// m97-style 128x128-tile grouped GEMM, BK=32, 4 waves/block,
// mfma_f32_16x16x32_bf16, global_load_lds width-16 staging.
// ws layout: [xb 64MB][w1t 64MB][w2t 64MB][h 256MB] = 448MB total.

#define B_ 4
#define E_ 8
#define N_ 1024
#define D_ 1024
#define H_ 4096

typedef unsigned short ushort_t;
typedef __attribute__((ext_vector_type(8))) __bf16 bf16x8;
typedef __attribute__((ext_vector_type(4))) float f32x4;
typedef __attribute__((ext_vector_type(4))) unsigned short ushort4v;

static __device__ __forceinline__ unsigned short f2bf(float f) {
    // round-to-nearest-even fp32 -> bf16 (no NaN handling needed here)
    unsigned u = __builtin_bit_cast(unsigned, f);
    unsigned r = 0x7FFFu + ((u >> 16) & 1u);
    return (unsigned short)((u + r) >> 16);
}

// ---- fp32 -> bf16 convert (layout-preserving), vectorized 4/thread ----
__global__ __launch_bounds__(256) void cvt_f32_bf16(const float* __restrict__ in,
                                                    ushort_t* __restrict__ out, long n) {
    long i0 = ((long)blockIdx.x * 256 + (long)threadIdx.x) * 4;
    long stride = (long)gridDim.x * 256 * 4;
    for (long i = i0; i < n; i += stride) {
        float4 v = *(const float4*)(in + i);
        ushort4v o;
        o.x = f2bf(v.x);
        o.y = f2bf(v.y);
        o.z = f2bf(v.z);
        o.w = f2bf(v.w);
        *(ushort4v*)(out + i) = o;
    }
}

// ---- per-expert transpose + convert: in[e] is RxC fp32, out[e] is CxR bf16 ----
__global__ __launch_bounds__(256) void transpose_cvt(const float* __restrict__ in,
                                                     ushort_t* __restrict__ out,
                                                     int R, int C) {
    __shared__ float tile[64][65];  // +1 pad: conflict-free transposed read
    const int e = blockIdx.z;
    const float* inp = in + (size_t)e * R * C;
    ushort_t* outp = out + (size_t)e * R * C;
    const int r0 = blockIdx.y * 64;
    const int c0 = blockIdx.x * 64;
    const int tx = threadIdx.x & 63;
    const int ty = threadIdx.x >> 6;  // 0..3
#pragma unroll
    for (int k = 0; k < 16; ++k) {
        int r = ty + k * 4;
        tile[r][tx] = inp[(size_t)(r0 + r) * C + (c0 + tx)];
    }
    __syncthreads();
#pragma unroll
    for (int k = 0; k < 16; ++k) {
        int c = ty + k * 4;
        outp[(size_t)(c0 + c) * R + (r0 + tx)] = f2bf(tile[tx][c]);
    }
}

// ---- grouped GEMM, B^T operand: C[g] = A[g](MxK) * B[e](KxN), BT is [E][N][K] ----
// EPI=0: C = gelu(A*B + bias) as bf16 (hidden).  EPI=1: C = A*B + bias as fp32 (out).
template <int EPI>
__global__ __launch_bounds__(256) void gemm_bt(const ushort_t* __restrict__ A,
                                               const ushort_t* __restrict__ BT,
                                               const float* __restrict__ bias,
                                               void* __restrict__ Cout,
                                               int M, int Nn, int K) {
    __shared__ __align__(16) ushort_t ldsA[128 * 32];
    __shared__ __align__(16) ushort_t ldsB[128 * 32];

    const int g = blockIdx.z;
    const int e = g & (E_ - 1);
    const ushort_t* Ag = A + (size_t)g * M * K;
    const ushort_t* BTg = BT + (size_t)e * Nn * K;
    const float* biasE = bias + (size_t)e * Nn;

    const int row0 = blockIdx.y * 128;
    const int col0 = blockIdx.x * 128;
    const int tid = threadIdx.x;
    const int wid = tid >> 6;
    const int lane = tid & 63;
    const int wr = wid >> 1;  // wave row 0..1 (64 rows each)
    const int wc = wid & 1;   // wave col 0..1 (64 cols each)
    const int lr = lane & 15;
    const int lkg = lane >> 4;  // k-group 0..3

    f32x4 acc[4][4];
#pragma unroll
    for (int m = 0; m < 4; ++m)
#pragma unroll
        for (int n = 0; n < 4; ++n) acc[m][n] = (f32x4){0.f, 0.f, 0.f, 0.f};

    // staging: each wave stages 16 rows x 32 cols per round, 2 rounds => 128 rows.
    // LDS dest is wave-uniform base + lane*16 (global_load_lds constraint);
    // per-lane GLOBAL address chosen to match: lane l -> row wid*16 + l/4,
    // cols (l%4)*8 .. +8.
    const int s_r = wid * 16 + (lane >> 2);
    const int s_c = (lane & 3) * 8;
    const ushort_t* aptr0 = Ag + (size_t)(row0 + s_r) * K + s_c;
    const ushort_t* aptr1 = Ag + (size_t)(row0 + 64 + s_r) * K + s_c;
    const ushort_t* bptr0 = BTg + (size_t)(col0 + s_r) * K + s_c;
    const ushort_t* bptr1 = BTg + (size_t)(col0 + 64 + s_r) * K + s_c;
    ushort_t* lA0 = &ldsA[(wid * 16) * 32];
    ushort_t* lA1 = &ldsA[(64 + wid * 16) * 32];
    ushort_t* lB0 = &ldsB[(wid * 16) * 32];
    ushort_t* lB1 = &ldsB[(64 + wid * 16) * 32];

    for (int k0 = 0; k0 < K; k0 += 32) {
        __builtin_amdgcn_global_load_lds(
            (const __attribute__((address_space(1))) void*)(aptr0 + k0),
            (__attribute__((address_space(3))) void*)lA0, 16, 0, 0);
        __builtin_amdgcn_global_load_lds(
            (const __attribute__((address_space(1))) void*)(aptr1 + k0),
            (__attribute__((address_space(3))) void*)lA1, 16, 0, 0);
        __builtin_amdgcn_global_load_lds(
            (const __attribute__((address_space(1))) void*)(bptr0 + k0),
            (__attribute__((address_space(3))) void*)lB0, 16, 0, 0);
        __builtin_amdgcn_global_load_lds(
            (const __attribute__((address_space(1))) void*)(bptr1 + k0),
            (__attribute__((address_space(3))) void*)lB1, 16, 0, 0);
        __syncthreads();  // drains vmcnt before LDS reads

        bf16x8 af[4], bfr[4];
#pragma unroll
        for (int m = 0; m < 4; ++m)
            af[m] = *(const bf16x8*)&ldsA[(wr * 64 + m * 16 + lr) * 32 + lkg * 8];
#pragma unroll
        for (int n = 0; n < 4; ++n)
            bfr[n] = *(const bf16x8*)&ldsB[(wc * 64 + n * 16 + lr) * 32 + lkg * 8];
#pragma unroll
        for (int m = 0; m < 4; ++m)
#pragma unroll
            for (int n = 0; n < 4; ++n)
                acc[m][n] = __builtin_amdgcn_mfma_f32_16x16x32_bf16(af[m], bfr[n],
                                                                    acc[m][n], 0, 0, 0);
        __syncthreads();  // protect LDS from next-iter staging
    }

    // epilogue: C/D layout col=lane&15, row=(lane>>4)*4+reg  [measured m89]
    if constexpr (EPI == 0) {
        ushort_t* Cg = (ushort_t*)Cout + (size_t)g * M * Nn;
#pragma unroll
        for (int m = 0; m < 4; ++m) {
#pragma unroll
            for (int n = 0; n < 4; ++n) {
                const int col = col0 + wc * 64 + n * 16 + lr;
                const float bv = biasE[col];
#pragma unroll
                for (int e2 = 0; e2 < 4; ++e2) {
                    const int row = row0 + wr * 64 + m * 16 + lkg * 4 + e2;
                    float v = acc[m][n][e2] + bv;
                    // jax.nn.gelu default (approximate=True, tanh form)
                    float u = 0.7978845608f * (v + 0.044715f * v * v * v);
                    float t = __expf(-2.0f * fabsf(u));
                    float th = (1.0f - t) / (1.0f + t);
                    th = (u < 0.f) ? -th : th;
                    float go = 0.5f * v * (1.0f + th);
                    Cg[(size_t)row * Nn + col] = f2bf(go);
                }
            }
        }
    } else {
        float* Cg = (float*)Cout + (size_t)g * M * Nn;
#pragma unroll
        for (int m = 0; m < 4; ++m) {
#pragma unroll
            for (int n = 0; n < 4; ++n) {
                const int col = col0 + wc * 64 + n * 16 + lr;
                const float bv = biasE[col];
#pragma unroll
                for (int e2 = 0; e2 < 4; ++e2) {
                    const int row = row0 + wr * 64 + m * 16 + lkg * 4 + e2;
                    Cg[(size_t)row * Nn + col] = acc[m][n][e2] + bv;
                }
            }
        }
    }
}

extern "C" void kernel_launch(void* const* d_in, const int* in_sizes, int n_in,
                              void* d_out, int out_size, void* d_ws, size_t ws_size,
                              hipStream_t stream) {
    const float* x = (const float*)d_in[0];
    const float* w1 = (const float*)d_in[1];
    const float* b1 = (const float*)d_in[2];
    const float* w2 = (const float*)d_in[3];
    const float* b2 = (const float*)d_in[4];
    float* out = (float*)d_out;

    constexpr size_t XB_OFF = 0;                       // 64 MB bf16 x
    constexpr size_t W1T_OFF = 64ull << 20;            // 64 MB bf16 w1^T [E][H][D]
    constexpr size_t W2T_OFF = 128ull << 20;           // 64 MB bf16 w2^T [E][D][H]
    constexpr size_t HB_OFF = 192ull << 20;            // 256 MB bf16 hidden [B*E][N][H]

    char* ws = (char*)d_ws;
    ushort_t* xb = (ushort_t*)(ws + XB_OFF);
    ushort_t* w1t = (ushort_t*)(ws + W1T_OFF);
    ushort_t* w2t = (ushort_t*)(ws + W2T_OFF);
    ushort_t* hb = (ushort_t*)(ws + HB_OFF);

    // 1) converts / transposes (bf16 staging for MFMA)
    cvt_f32_bf16<<<2048, 256, 0, stream>>>(x, xb, (long)B_ * E_ * N_ * D_);
    transpose_cvt<<<dim3(H_ / 64, D_ / 64, E_), 256, 0, stream>>>(w1, w1t, D_, H_);
    transpose_cvt<<<dim3(D_ / 64, H_ / 64, E_), 256, 0, stream>>>(w2, w2t, H_, D_);

    // 2) h = gelu(x @ w1 + b1)   (per group g = b*E + e, expert e = g % 8)
    gemm_bt<0><<<dim3(H_ / 128, N_ / 128, B_ * E_), 256, 0, stream>>>(
        xb, w1t, b1, hb, N_, H_, D_);

    // 3) out = h @ w2 + b2
    gemm_bt<1><<<dim3(D_ / 128, N_ / 128, B_ * E_), 256, 0, stream>>>(
        hb, w2t, b2, out, N_, D_, H_);
}